// Round 4
// baseline (331.641 us; speedup 1.0000x reference)
//
#include <hip/hip_runtime.h>
#include <hip/hip_bf16.h>
#include <math.h>

// Dims: x[8192,4096] A[128,4096] B[8,4096,16] Wr[8,4096] br[8] -> out[8192,4096]
// Fused: per block of 16 tokens:
//   phase1: S[16][144] = x * W1^T   (W1 rows: 0..127=A, 128..135=Wr, 136..143=0)
//           K=4096 split across 8 waves (512 each), partials reduced in LDS
//   softmax over cols 128..135 -> scale; W2s[16][128] bf16 in LDS
//   phase2: out[16][4096] = W2s * Bt^T, N split across 8 waves (512 each)
#define D_DIM 4096
#define O_DIM 4096

typedef __attribute__((ext_vector_type(8))) short short8;
typedef __attribute__((ext_vector_type(4))) float floatx4;

__device__ inline unsigned short f2bf(float f) {
    union { float f; unsigned u; } v; v.f = f;
    unsigned r = v.u + 0x7FFF + ((v.u >> 16) & 1);   // RNE
    return (unsigned short)(r >> 16);
}

// packed f32x2 -> bf16x2 (compiler lowers to v_cvt_pk_bf16_f32, RNE)
__device__ inline unsigned cvt2(float lo, float hi) {
    __hip_bfloat162 h2 = __float22bfloat162_rn(make_float2(lo, hi));
    union { __hip_bfloat162 h; unsigned u; } c; c.h = h2;
    return c.u;
}

// ---------- merged prep: W1bf [144][4096] bf16 (A,Wr,zeros) + Btbf [4096][128] ----------
__global__ __launch_bounds__(256) void k0_prep(const float* __restrict__ A,
                                               const float* __restrict__ Wr,
                                               const float* __restrict__ B,
                                               unsigned short* __restrict__ W1bf,
                                               unsigned short* __restrict__ Btbf) {
    if (blockIdx.x < 576) {
        int e = (blockIdx.x * 256 + threadIdx.x) * 4;    // 144*4096 = 589824 elems
        int row = e >> 12;
        int col = e & 4095;
        float4 v;
        if (row < 128)      v = *(const float4*)(A + (size_t)row * D_DIM + col);
        else if (row < 136) v = *(const float4*)(Wr + (size_t)(row - 128) * D_DIM + col);
        else                v = make_float4(0.f, 0.f, 0.f, 0.f);
        ushort4 o; o.x = f2bf(v.x); o.y = f2bf(v.y); o.z = f2bf(v.z); o.w = f2bf(v.w);
        *(ushort4*)(W1bf + e) = o;
    } else {
        int e = ((blockIdx.x - 576) * 256 + threadIdx.x) * 4;   // 4096*128 = 524288 elems
        int o = e >> 7;
        int k = e & 127;          // k%4==0, so all 4 elems share h
        int h = k >> 4;
        int r = k & 15;
        float4 v = *(const float4*)(B + (size_t)h * (O_DIM * 16) + (size_t)o * 16 + r);
        ushort4 w; w.x = f2bf(v.x); w.y = f2bf(v.y); w.z = f2bf(v.z); w.w = f2bf(v.w);
        *(ushort4*)(Btbf + e) = w;
    }
}

// ---------- fused kernel ----------
// grid = 512 blocks (16 tokens each), block = 512 threads (8 waves).
// LDS: Sred 73728 B + W2s 4224 B = 77952 B -> 2 blocks/CU; VGPR capped 128 (4 waves/SIMD).
__global__ __launch_bounds__(512, 4) void kf_fused(const float* __restrict__ X,
                                                   const unsigned short* __restrict__ W1bf,
                                                   const unsigned short* __restrict__ Btbf,
                                                   const float* __restrict__ br,
                                                   float* __restrict__ out) {
    __shared__ float Sred[8][16][144];          // per-wave GEMM1 partials; reused as bounce
    __shared__ unsigned short W2s[16][132];     // softmax-scaled low-rank, bf16 (+4 pad)
    const int tid  = threadIdx.x;
    const int wave = tid >> 6;
    const int lane = tid & 63;
    const int lrow = lane & 15;
    const int quad = lane >> 4;
    const int m0   = blockIdx.x * 16;

    // ===== phase 1: S_partial[16][144] for this wave's K-slice (512 wide) =====
    const int kb = wave * 512;
    floatx4 acc[9];
    #pragma unroll
    for (int n = 0; n < 9; ++n) acc[n] = (floatx4)(0.f);

    const float*          xrow  = X    + (size_t)(m0 + lrow) * D_DIM + kb + quad * 8;
    const unsigned short* wbase = W1bf + (size_t)lrow * D_DIM + kb + quad * 8;

    #pragma unroll 2
    for (int ks = 0; ks < 16; ++ks) {
        // A-frag: 8 fp32 direct from HBM, cvt_pk to bf16
        float4 x0 = *(const float4*)(xrow + ks * 32);
        float4 x1 = *(const float4*)(xrow + ks * 32 + 4);
        union { unsigned u[4]; short8 s; } a;
        a.u[0] = cvt2(x0.x, x0.y); a.u[1] = cvt2(x0.z, x0.w);
        a.u[2] = cvt2(x1.x, x1.y); a.u[3] = cvt2(x1.z, x1.w);
        #pragma unroll
        for (int n = 0; n < 9; ++n) {
            short8 b = *(const short8*)(wbase + (size_t)n * (16 * D_DIM) + ks * 32);
            acc[n] = __builtin_amdgcn_mfma_f32_16x16x32_bf16(a.s, b, acc[n], 0, 0, 0);
        }
    }

    // write this wave's partial tile to LDS
    #pragma unroll
    for (int n = 0; n < 9; ++n)
        #pragma unroll
        for (int reg = 0; reg < 4; ++reg)
            Sred[wave][quad * 4 + reg][n * 16 + lrow] = acc[n][reg];   // row=(lane>>4)*4+reg, col=lane&15
    __syncthreads();

    // ===== reduce 8 partials -> Sred[0] =====
    for (int idx = tid; idx < 2304; idx += 512) {        // 16*144 cells
        int row = idx / 144;
        int col = idx - row * 144;
        float s = Sred[0][row][col];
        #pragma unroll
        for (int p = 1; p < 8; ++p) s += Sred[p][row][col];
        Sred[0][row][col] = s;
    }
    __syncthreads();

    // ===== softmax (cols 128..135) -> per-head scale in cols 136..143 =====
    if (tid < 16) {
        float l[8]; float m = -1e30f;
        #pragma unroll
        for (int h = 0; h < 8; ++h) { l[h] = Sred[0][tid][128 + h] + br[h]; m = fmaxf(m, l[h]); }
        float s = 0.f;
        #pragma unroll
        for (int h = 0; h < 8; ++h) { l[h] = __expf(l[h] - m); s += l[h]; }
        float inv = 16.0f / s;                           // H * SCALING = 16
        #pragma unroll
        for (int h = 0; h < 8; ++h) Sred[0][tid][136 + h] = l[h] * inv;
    }
    __syncthreads();

    // ===== build W2s bf16 [16][128]: low * per-head scale =====
    {
        int row = tid >> 5;                              // 512 thr * 4 elems = 2048 cells
        int c   = (tid & 31) * 4;
        float sc = Sred[0][row][136 + (c >> 4)];
        float4 v = *(const float4*)&Sred[0][row][c];
        ushort4 o;
        o.x = f2bf(v.x * sc); o.y = f2bf(v.y * sc);
        o.z = f2bf(v.z * sc); o.w = f2bf(v.w * sc);
        *(ushort4*)&W2s[row][c] = o;
    }
    __syncthreads();

    // ===== phase 2: out[16][wave*512 .. +512] = W2s * Bt^T =====
    float* bounce = &Sred[0][0][0] + wave * (16 * 132);  // 8448 B per wave, dead Sred reuse

    short8 afr[4];                                       // A-frags: one per kstep, reused all n
    #pragma unroll
    for (int ks = 0; ks < 4; ++ks)
        afr[ks] = *(const short8*)&W2s[lrow][ks * 32 + quad * 8];

    const int nb = wave * 512;
    for (int nc = 0; nc < 4; ++nc) {                     // 4 chunks of 128 cols
        const int n0c = nb + nc * 128;
        floatx4 acc2[8];
        #pragma unroll
        for (int n = 0; n < 8; ++n) acc2[n] = (floatx4)(0.f);

        #pragma unroll
        for (int ks = 0; ks < 4; ++ks)
            #pragma unroll
            for (int n = 0; n < 8; ++n) {
                short8 b = *(const short8*)(Btbf + (size_t)(n0c + n * 16 + lrow) * 128 + ks * 32 + quad * 8);
                acc2[n] = __builtin_amdgcn_mfma_f32_16x16x32_bf16(afr[ks], b, acc2[n], 0, 0, 0);
            }

        // bounce through LDS (per-wave region, wave-internal => no barrier needed)
        #pragma unroll
        for (int n = 0; n < 8; ++n)
            #pragma unroll
            for (int reg = 0; reg < 4; ++reg)
                bounce[(quad * 4 + reg) * 132 + n * 16 + lrow] = acc2[n][reg];

        #pragma unroll
        for (int i = 0; i < 8; ++i) {
            int idx = lane + i * 64;                     // 0..511
            int row = idx >> 5;                          // 32 float4 per row-chunk
            int u   = idx & 31;
            floatx4 v = *(const floatx4*)&bounce[row * 132 + u * 4];
            __builtin_nontemporal_store(v,
                (floatx4*)(out + (size_t)(m0 + row) * O_DIM + n0c + u * 4));
        }
    }
}

extern "C" void kernel_launch(void* const* d_in, const int* in_sizes, int n_in,
                              void* d_out, int out_size, void* d_ws, size_t ws_size,
                              hipStream_t stream) {
    const float* x  = (const float*)d_in[0];
    const float* A  = (const float*)d_in[1];
    const float* B  = (const float*)d_in[2];
    const float* Wr = (const float*)d_in[3];
    const float* br = (const float*)d_in[4];
    float* out = (float*)d_out;

    // ws layout: W1bf 144*4096 bf16 = 589824 ushort; Btbf 4096*128 bf16 = 524288 ushort (~2.2 MB)
    unsigned short* W1bf = (unsigned short*)d_ws;
    unsigned short* Btbf = W1bf + 589824;

    k0_prep<<<dim3(1088), dim3(256), 0, stream>>>(A, Wr, B, W1bf, Btbf);
    kf_fused<<<dim3(512), dim3(512), 0, stream>>>(x, W1bf, Btbf, br, out);
}